// Round 6
// baseline (40.488 us; speedup 1.0000x reference)
//
#include <hip/hip_runtime.h>
#include <stdint.h>

// Problem constants (match reference)
#define BB 8
#define SS 4096
#define TOKEN_BITS 12
#define EMB 1024
#define NB 12
#define TABLE 4096
#define POS_BITS 13
#define SPB 8   // sequence positions per block in ram_embed

typedef float f32x4 __attribute__((ext_vector_type(4)));

// ---------------------------------------------------------------------------
// Kernel 1 (fused build): one block per neuron-group g (neurons 4g..4g+3).
// Stage the 4 CONTIGUOUS table rows in LDS (64 KB) — the only pass over the
// 16 MB table, fully coalesced, 256 blocks = 1/CU. Then for all 4096 patterns
// compute the 4 neuron bits and write one byte remap_nib[pat*256 + g].
//
// Address math hoisted via XOR-mask decomposition: pat = t + 256*m (t = lane's
// fixed low 8 bits, m = 0..15). addr(pat) = addr_low(t) ^ hi[b] for each set
// bit b of m, where hi[b] = OR of (1<<(11-j)) over j with conn[j]==8+b.
// Contributions occupy disjoint bit positions (position depends on j only),
// so XOR/OR are equivalent. All arrays compile-time indexed (no scratch).
// ---------------------------------------------------------------------------
__global__ __launch_bounds__(256) void build_nib(const float* __restrict__ tables,
                                                 const int* __restrict__ conn,
                                                 uint8_t* __restrict__ remap_nib) {
    __shared__ float rows[4 * TABLE];           // 64 KB
    const int g = blockIdx.x;                   // 0..255
    const int t = threadIdx.x;

    // stage 4 contiguous rows (64 KB), coalesced f32x4
    const f32x4* src = (const f32x4*)(tables + (size_t)(4 * g) * TABLE);
    f32x4* dst = (f32x4*)rows;
#pragma unroll
    for (int i = 0; i < 16; ++i)
        dst[t + 256 * i] = src[t + 256 * i];

    // per-neuron address decomposition (overlaps with staging latency)
    uint32_t addr_low[4], hi[4][4];
#pragma unroll
    for (int u = 0; u < 4; ++u) {
        uint32_t al = 0, h0 = 0, h1 = 0, h2 = 0, h3 = 0;
        for (int j = 0; j < NB; ++j) {
            int c = conn[(size_t)(4 * g + u) * NB + j];   // block-uniform -> s_loads
            uint32_t bp = 1u << (NB - 1 - j);             // j=0 is MSB (reference)
            if (c < 8)        al |= ((t >> c) & 1) ? bp : 0u;
            else if (c == 8)  h0 |= bp;
            else if (c == 9)  h1 |= bp;
            else if (c == 10) h2 |= bp;
            else              h3 |= bp;
        }
        addr_low[u] = al;
        hi[u][0] = h0; hi[u][1] = h1; hi[u][2] = h2; hi[u][3] = h3;
    }
    __syncthreads();

#pragma unroll
    for (int m = 0; m < 16; ++m) {
        const int pat = t + 256 * m;
        uint32_t nib = 0;
#pragma unroll
        for (int u = 0; u < 4; ++u) {
            uint32_t addr = addr_low[u];
            if (m & 1) addr ^= hi[u][0];
            if (m & 2) addr ^= hi[u][1];
            if (m & 4) addr ^= hi[u][2];
            if (m & 8) addr ^= hi[u][3];
            nib |= (rows[u * TABLE + addr] != 0.0f) ? (1u << u) : 0u;
        }
        remap_nib[(size_t)pat * 256 + g] = (uint8_t)nib;  // scattered 1B, L2-merged
    }
}

// ---------------------------------------------------------------------------
// Kernel 2: main embedding (R3/R5 structure). One block per SPB=8 rows.
// Thread t reads ONE byte remap_nib[pat*256 + t] (64 consecutive bytes/wave,
// single L2 line) = the 4 neuron bits for its output nibble; integer XOR with
// the binary position nibble; one plain f32x4 store per row.
// ---------------------------------------------------------------------------
__global__ __launch_bounds__(256) void ram_embed(const int* __restrict__ tokens,
                                                 const uint8_t* __restrict__ remap_nib,
                                                 float* __restrict__ out) {
    const int g0 = blockIdx.x * SPB;            // first b*S+s row index
    const int t  = threadIdx.x;
    __shared__ int tok[SPB * TOKEN_BITS];
    __shared__ int pats[SPB];
    if (t < SPB * TOKEN_BITS)
        tok[t] = tokens[(size_t)g0 * TOKEN_BITS + t];
    __syncthreads();
    if (t < SPB) {
        int p = 0;
#pragma unroll
        for (int j = 0; j < TOKEN_BITS; ++j)
            p |= (tok[t * TOKEN_BITS + j] & 1) << j;
        pats[t] = p;
    }
    __syncthreads();

    const int n0 = t * 4;
    int sh[4];
#pragma unroll
    for (int u = 0; u < 4; ++u)
        sh[u] = POS_BITS - 1 - ((n0 + u) % POS_BITS);
    const int sbase = g0 & (SS - 1);            // SPB divides SS, so b is fixed

    for (int k = 0; k < SPB; ++k) {
        const int s   = sbase + k;
        uint32_t nib  = remap_nib[(size_t)pats[k] * 256 + t];
        uint32_t pn   =  (uint32_t)((s >> sh[0]) & 1)
                      | ((uint32_t)((s >> sh[1]) & 1) << 1)
                      | ((uint32_t)((s >> sh[2]) & 1) << 2)
                      | ((uint32_t)((s >> sh[3]) & 1) << 3);
        uint32_t x = nib ^ pn;
        f32x4 o;
        o.x = (x & 1u) ? 1.0f : 0.0f;
        o.y = (x & 2u) ? 1.0f : 0.0f;
        o.z = (x & 4u) ? 1.0f : 0.0f;
        o.w = (x & 8u) ? 1.0f : 0.0f;
        *(f32x4*)(out + (size_t)(g0 + k) * EMB + n0) = o;
    }
}

// ---------------------------------------------------------------------------
extern "C" void kernel_launch(void* const* d_in, const int* in_sizes, int n_in,
                              void* d_out, int out_size, void* d_ws, size_t ws_size,
                              hipStream_t stream) {
    const int*   tokens = (const int*)d_in[0];
    const float* tables = (const float*)d_in[1];
    const int*   conn   = (const int*)d_in[2];
    float*       out    = (float*)d_out;

    // ws layout: [0, 1MB) remap_nib[pat][group] — one nibble-byte per
    // (pattern, 4-neuron group)
    uint8_t* remap_nib = (uint8_t*)d_ws;

    build_nib<<<EMB / 4, 256, 0, stream>>>(tables, conn, remap_nib);
    ram_embed<<<BB * SS / SPB, 256, 0, stream>>>(tokens, remap_nib, out);
}